// Round 1
// baseline (413.741 us; speedup 1.0000x reference)
//
#include <hip/hip_runtime.h>
#include <math.h>

#define DIMS 128
#define GD 256
#define MAXB 1024
#define NSLOT 8   // edge slots per reduce block (256 thr / 32 dim-groups)

// ---------- helpers ----------
__device__ __forceinline__ float4 f4_add(float4 a, float4 b) {
    return make_float4(a.x + b.x, a.y + b.y, a.z + b.z, a.w + b.w);
}
__device__ __forceinline__ float4 f4_min(float4 a, float4 b) {
    return make_float4(fminf(a.x, b.x), fminf(a.y, b.y), fminf(a.z, b.z), fminf(a.w, b.w));
}
__device__ __forceinline__ float4 f4_max(float4 a, float4 b) {
    return make_float4(fmaxf(a.x, b.x), fmaxf(a.y, b.y), fmaxf(a.z, b.z), fmaxf(a.w, b.w));
}

template <int OP>
__device__ __forceinline__ float4 comb(float4 a, float4 b) {
    if (OP == 0) return f4_add(a, b);
    if (OP == 1) return f4_min(a, b);
    return f4_max(a, b);
}

// reduce the 8 edge-slots (stride 32 in tid) down to slot 0; result valid for tid<32
template <int OP>
__device__ __forceinline__ float4 slot_reduce(float4 v, float4* red) {
    int t = threadIdx.x;
    __syncthreads();
    red[t] = v;
    __syncthreads();
    for (int off = 128; off >= 32; off >>= 1) {
        if (t < off) red[t] = comb<OP>(red[t], red[t + off]);
        __syncthreads();
    }
    return red[t & 31];
}

// ---------- kernels ----------
__global__ void hist_kernel(const int* __restrict__ e_index, const int* __restrict__ batch,
                            int E, int B, int* __restrict__ hist) {
    __shared__ int lh[MAXB];
    for (int i = threadIdx.x; i < B; i += blockDim.x) lh[i] = 0;
    __syncthreads();
    int stride = gridDim.x * blockDim.x;
    for (int j = blockIdx.x * blockDim.x + threadIdx.x; j < E; j += stride) {
        int node = e_index[E + j];       // e_index[1][j]
        int b = batch[node];
        atomicAdd(&lh[b], 1);
    }
    __syncthreads();
    for (int i = threadIdx.x; i < B; i += blockDim.x)
        if (lh[i]) atomicAdd(&hist[i], lh[i]);
}

__global__ void scan_kernel(const int* __restrict__ hist, int* __restrict__ offs,
                            int* __restrict__ cursor, int B) {
    __shared__ int tmp[MAXB];
    int t = threadIdx.x;
    int v0 = (t < B) ? hist[t] : 0;
    tmp[t] = v0;
    __syncthreads();
    for (int d = 1; d < MAXB; d <<= 1) {
        int v = (t >= d) ? tmp[t - d] : 0;
        __syncthreads();
        tmp[t] += v;
        __syncthreads();
    }
    if (t < B) {
        int excl = tmp[t] - v0;          // exclusive prefix
        offs[t] = excl;
        cursor[t * 16] = excl;           // padded: 1 cursor per 64B line
    }
}

__global__ void scatter_kernel(const int* __restrict__ e_index, const int* __restrict__ batch,
                               int E, int* __restrict__ cursor, int* __restrict__ perm) {
    int stride = gridDim.x * blockDim.x;
    for (int j = blockIdx.x * blockDim.x + threadIdx.x; j < E; j += stride) {
        int node = e_index[E + j];
        int b = batch[node];
        int pos = atomicAdd(&cursor[b * 16], 1);
        perm[pos] = j;
    }
}

__global__ void __launch_bounds__(256)
reduce_kernel(const float* __restrict__ e, const int* __restrict__ perm,
              const int* __restrict__ offs, const int* __restrict__ hist,
              float* __restrict__ gbuf) {
    int g = blockIdx.x;
    int start = offs[g];
    int cnt = hist[g];
    int c = threadIdx.x & 31;   // dim group: dims 4c..4c+3
    int s = threadIdx.x >> 5;   // edge slot 0..7

    float4 sm = make_float4(0.f, 0.f, 0.f, 0.f);
    float4 sq = make_float4(0.f, 0.f, 0.f, 0.f);
    float4 mn = make_float4(INFINITY, INFINITY, INFINITY, INFINITY);
    float4 mx = make_float4(-INFINITY, -INFINITY, -INFINITY, -INFINITY);

    int i = s;
    // 2x unrolled: two independent row loads in flight per iteration
    for (; i + NSLOT < cnt; i += 2 * NSLOT) {
        int r0 = perm[start + i];
        int r1 = perm[start + i + NSLOT];
        float4 v0 = *reinterpret_cast<const float4*>(e + (size_t)r0 * DIMS + c * 4);
        float4 v1 = *reinterpret_cast<const float4*>(e + (size_t)r1 * DIMS + c * 4);
        sm = f4_add(sm, v0); sq = f4_add(sq, make_float4(v0.x*v0.x, v0.y*v0.y, v0.z*v0.z, v0.w*v0.w));
        mn = f4_min(mn, v0); mx = f4_max(mx, v0);
        sm = f4_add(sm, v1); sq = f4_add(sq, make_float4(v1.x*v1.x, v1.y*v1.y, v1.z*v1.z, v1.w*v1.w));
        mn = f4_min(mn, v1); mx = f4_max(mx, v1);
    }
    for (; i < cnt; i += NSLOT) {
        int r = perm[start + i];
        float4 v = *reinterpret_cast<const float4*>(e + (size_t)r * DIMS + c * 4);
        sm = f4_add(sm, v); sq = f4_add(sq, make_float4(v.x*v.x, v.y*v.y, v.z*v.z, v.w*v.w));
        mn = f4_min(mn, v); mx = f4_max(mx, v);
    }

    __shared__ float4 red[256];
    float4 smr = slot_reduce<0>(sm, red);
    float4 sqr = slot_reduce<0>(sq, red);
    float4 mnr = slot_reduce<1>(mn, red);
    float4 mxr = slot_reduce<2>(mx, red);

    if (threadIdx.x < 32) {
        float fc = (float)cnt;
        float fcm = fmaxf(fc, 1.0f);
        float4 mean = make_float4(smr.x / fcm, smr.y / fcm, smr.z / fcm, smr.w / fcm);
        // var_sum = sum(x^2) - sum(x)*mean  (== sum((x-mean)^2) for cnt>=1)
        float4 vs = make_float4(fmaxf(sqr.x - smr.x * mean.x, 0.f),
                                fmaxf(sqr.y - smr.y * mean.y, 0.f),
                                fmaxf(sqr.z - smr.z * mean.z, 0.f),
                                fmaxf(sqr.w - smr.w * mean.w, 0.f));
        float denom = fmaxf(fc - 1.0f, 1.0f) + 1e-6f;
        float4 sd = make_float4(sqrtf(vs.x / denom), sqrtf(vs.y / denom),
                                sqrtf(vs.z / denom), sqrtf(vs.w / denom));
        if (cnt == 0) {  // empty segment: torch_scatter fills min/max with 0
            mnr = make_float4(0.f, 0.f, 0.f, 0.f);
            mxr = make_float4(0.f, 0.f, 0.f, 0.f);
        }
        float* row = gbuf + (size_t)g * (4 * DIMS);
        int d0 = c * 4;
        *reinterpret_cast<float4*>(row + 0 * DIMS + d0) = mean;
        *reinterpret_cast<float4*>(row + 1 * DIMS + d0) = mnr;
        *reinterpret_cast<float4*>(row + 2 * DIMS + d0) = mxr;
        *reinterpret_cast<float4*>(row + 3 * DIMS + d0) = sd;
    }
}

// out[r, col] = sum_k gbuf[r,k] * w[k,col] + bias[col]; 8 rows per block
__global__ void __launch_bounds__(256)
gemm_kernel(const float* __restrict__ gbuf, const float* __restrict__ w,
            const float* __restrict__ bias, float* __restrict__ out, int B) {
    __shared__ float gl[8 * 512];
    int r0 = blockIdx.x * 8;
    for (int i = threadIdx.x; i < 8 * 512; i += 256) {
        int r = r0 + (i >> 9);
        gl[i] = (r < B) ? gbuf[(size_t)r0 * 512 + i] : 0.f;
    }
    __syncthreads();
    int col = threadIdx.x;
    float acc[8];
    float bv = bias[col];
#pragma unroll
    for (int r = 0; r < 8; ++r) acc[r] = bv;
#pragma unroll 4
    for (int k = 0; k < 512; ++k) {
        float wv = w[k * GD + col];
#pragma unroll
        for (int r = 0; r < 8; ++r) acc[r] += gl[r * 512 + k] * wv;
    }
#pragma unroll
    for (int r = 0; r < 8; ++r) {
        int rr = r0 + r;
        if (rr < B) out[(size_t)rr * GD + col] = acc[r];
    }
}

// ---------- launch ----------
extern "C" void kernel_launch(void* const* d_in, const int* in_sizes, int n_in,
                              void* d_out, int out_size, void* d_ws, size_t ws_size,
                              hipStream_t stream) {
    const int*   e_index = (const int*)d_in[0];
    const float* e       = (const float*)d_in[1];
    const int*   batch   = (const int*)d_in[2];
    const float* fc_w    = (const float*)d_in[3];
    const float* fc_b    = (const float*)d_in[4];
    float* out = (float*)d_out;

    int E = in_sizes[1] / DIMS;
    int B = out_size / GD;

    // workspace layout (ints/floats, all 4B-aligned)
    int* hist   = (int*)d_ws;                 // B
    int* offs   = hist + MAXB;                // B
    int* cursor = offs + MAXB;                // B*16 (padded)
    int* perm   = cursor + MAXB * 16;         // E
    float* gbuf = (float*)(perm + E);         // B*512

    hipMemsetAsync(hist, 0, B * sizeof(int), stream);
    hist_kernel<<<1024, 256, 0, stream>>>(e_index, batch, E, B, hist);
    scan_kernel<<<1, MAXB, 0, stream>>>(hist, offs, cursor, B);
    scatter_kernel<<<1024, 256, 0, stream>>>(e_index, batch, E, cursor, perm);
    reduce_kernel<<<B, 256, 0, stream>>>(e, perm, offs, hist, gbuf);
    gemm_kernel<<<(B + 7) / 8, 256, 0, stream>>>(gbuf, fc_w, fc_b, out, B);
}

// Round 2
// 345.774 us; speedup vs baseline: 1.1966x; 1.1966x over previous
//
#include <hip/hip_runtime.h>
#include <math.h>

#define DIMS 128
#define GD 256
#define MAXB 1024
#define NSLOT 8   // edge slots per reduce block (256 thr / 32 dim-groups)
#define PARTS 4   // blocks per graph in reduce phase

typedef float vfloat4 __attribute__((ext_vector_type(4)));

// ---------- helpers ----------
__device__ __forceinline__ float4 ldnt(const float* p) {
    vfloat4 v = __builtin_nontemporal_load(reinterpret_cast<const vfloat4*>(p));
    return make_float4(v.x, v.y, v.z, v.w);
}
__device__ __forceinline__ float4 f4_add(float4 a, float4 b) {
    return make_float4(a.x + b.x, a.y + b.y, a.z + b.z, a.w + b.w);
}
__device__ __forceinline__ float4 f4_min(float4 a, float4 b) {
    return make_float4(fminf(a.x, b.x), fminf(a.y, b.y), fminf(a.z, b.z), fminf(a.w, b.w));
}
__device__ __forceinline__ float4 f4_max(float4 a, float4 b) {
    return make_float4(fmaxf(a.x, b.x), fmaxf(a.y, b.y), fmaxf(a.z, b.z), fmaxf(a.w, b.w));
}

template <int OP>
__device__ __forceinline__ float4 comb(float4 a, float4 b) {
    if (OP == 0) return f4_add(a, b);
    if (OP == 1) return f4_min(a, b);
    return f4_max(a, b);
}

// reduce the 8 edge-slots (stride 32 in tid) down to slot 0; result valid for tid<32
template <int OP>
__device__ __forceinline__ float4 slot_reduce(float4 v, float4* red) {
    int t = threadIdx.x;
    __syncthreads();
    red[t] = v;
    __syncthreads();
    for (int off = 128; off >= 32; off >>= 1) {
        if (t < off) red[t] = comb<OP>(red[t], red[t + off]);
        __syncthreads();
    }
    return red[t & 31];
}

// ---------- kernels ----------
__global__ void hist_kernel(const int* __restrict__ e_index, const int* __restrict__ batch,
                            int E, int B, int* __restrict__ hist,
                            unsigned short* __restrict__ eb) {
    __shared__ int lh[MAXB];
    for (int i = threadIdx.x; i < B; i += blockDim.x) lh[i] = 0;
    __syncthreads();
    int stride = gridDim.x * blockDim.x;
    for (int j = blockIdx.x * blockDim.x + threadIdx.x; j < E; j += stride) {
        int node = e_index[E + j];       // e_index[1][j]
        int b = batch[node];
        eb[j] = (unsigned short)b;       // cache graph id per edge for pass 2
        atomicAdd(&lh[b], 1);
    }
    __syncthreads();
    for (int i = threadIdx.x; i < B; i += blockDim.x)
        if (lh[i]) atomicAdd(&hist[i], lh[i]);
}

__global__ void scan_kernel(const int* __restrict__ hist, int* __restrict__ offs,
                            int* __restrict__ cursor, int B) {
    __shared__ int tmp[MAXB];
    int t = threadIdx.x;
    int v0 = (t < B) ? hist[t] : 0;
    tmp[t] = v0;
    __syncthreads();
    for (int d = 1; d < MAXB; d <<= 1) {
        int v = (t >= d) ? tmp[t - d] : 0;
        __syncthreads();
        tmp[t] += v;
        __syncthreads();
    }
    if (t < B) {
        int excl = tmp[t] - v0;          // exclusive prefix
        offs[t] = excl;
        cursor[t * 16] = excl;           // padded: 1 cursor per 64B line
    }
}

__global__ void scatter_kernel(const unsigned short* __restrict__ eb,
                               int E, int* __restrict__ cursor, int* __restrict__ perm) {
    int stride = gridDim.x * blockDim.x;
    for (int j = blockIdx.x * blockDim.x + threadIdx.x; j < E; j += stride) {
        int b = eb[j];
        int pos = atomicAdd(&cursor[b * 16], 1);
        perm[pos] = j;
    }
}

// one block per (graph, part): partials {sum, min, max, sumsq} -> pbuf[g*PARTS+p][512]
__global__ void __launch_bounds__(256)
reduce_kernel(const float* __restrict__ e, const int* __restrict__ perm,
              const int* __restrict__ offs, const int* __restrict__ hist,
              float* __restrict__ pbuf) {
    int bid = blockIdx.x;
    int g = bid >> 2;                // PARTS == 4
    int p = bid & 3;
    int start = offs[g];
    int cnt = hist[g];
    int chunk = (cnt + PARTS - 1) / PARTS;
    int base = start + p * chunk;
    int cnt_p = cnt - p * chunk;
    if (cnt_p > chunk) cnt_p = chunk;
    if (cnt_p < 0) cnt_p = 0;
    const int* pp = perm + base;

    int c = threadIdx.x & 31;   // dim group: dims 4c..4c+3
    int s = threadIdx.x >> 5;   // edge slot 0..7

    float4 sm = make_float4(0.f, 0.f, 0.f, 0.f);
    float4 sq = make_float4(0.f, 0.f, 0.f, 0.f);
    float4 mn = make_float4(INFINITY, INFINITY, INFINITY, INFINITY);
    float4 mx = make_float4(-INFINITY, -INFINITY, -INFINITY, -INFINITY);

    int i = s;
    int r0n = 0, r1n = 0;
    if (i + NSLOT < cnt_p) { r0n = pp[i]; r1n = pp[i + NSLOT]; }
    for (; i + NSLOT < cnt_p; i += 2 * NSLOT) {
        int r0 = r0n, r1 = r1n;
        int nx = i + 2 * NSLOT;
        if (nx + NSLOT < cnt_p) { r0n = pp[nx]; r1n = pp[nx + NSLOT]; }  // prefetch next pair
        float4 v0 = ldnt(e + (size_t)r0 * DIMS + c * 4);
        float4 v1 = ldnt(e + (size_t)r1 * DIMS + c * 4);
        sm = f4_add(sm, v0); sq = f4_add(sq, make_float4(v0.x*v0.x, v0.y*v0.y, v0.z*v0.z, v0.w*v0.w));
        mn = f4_min(mn, v0); mx = f4_max(mx, v0);
        sm = f4_add(sm, v1); sq = f4_add(sq, make_float4(v1.x*v1.x, v1.y*v1.y, v1.z*v1.z, v1.w*v1.w));
        mn = f4_min(mn, v1); mx = f4_max(mx, v1);
    }
    for (; i < cnt_p; i += NSLOT) {
        int r = pp[i];
        float4 v = ldnt(e + (size_t)r * DIMS + c * 4);
        sm = f4_add(sm, v); sq = f4_add(sq, make_float4(v.x*v.x, v.y*v.y, v.z*v.z, v.w*v.w));
        mn = f4_min(mn, v); mx = f4_max(mx, v);
    }

    __shared__ float4 red[256];
    float4 smr = slot_reduce<0>(sm, red);
    float4 sqr = slot_reduce<0>(sq, red);
    float4 mnr = slot_reduce<1>(mn, red);
    float4 mxr = slot_reduce<2>(mx, red);

    if (threadIdx.x < 32) {
        float* row = pbuf + (size_t)bid * (4 * DIMS);
        int d0 = c * 4;
        *reinterpret_cast<float4*>(row + 0 * DIMS + d0) = smr;
        *reinterpret_cast<float4*>(row + 1 * DIMS + d0) = mnr;
        *reinterpret_cast<float4*>(row + 2 * DIMS + d0) = mxr;
        *reinterpret_cast<float4*>(row + 3 * DIMS + d0) = sqr;
    }
}

// merge PARTS partials per graph, finalize mean/min/max/std -> gbuf[g][512]
__global__ void __launch_bounds__(256)
combine_kernel(const float* __restrict__ pbuf, const int* __restrict__ hist,
               float* __restrict__ gbuf, int B) {
    int idx = blockIdx.x * blockDim.x + threadIdx.x;
    if (idx >= B * DIMS) return;
    int g = idx >> 7;
    int d = idx & (DIMS - 1);
    float sm = 0.f, sq = 0.f, mn = INFINITY, mx = -INFINITY;
#pragma unroll
    for (int p = 0; p < PARTS; ++p) {
        const float* r = pbuf + (size_t)(g * PARTS + p) * (4 * DIMS);
        sm += r[d];
        mn = fminf(mn, r[DIMS + d]);
        mx = fmaxf(mx, r[2 * DIMS + d]);
        sq += r[3 * DIMS + d];
    }
    int cnt = hist[g];
    float fc = (float)cnt;
    float fcm = fmaxf(fc, 1.0f);
    float mean = sm / fcm;
    float vs = fmaxf(sq - sm * mean, 0.f);
    float denom = fmaxf(fc - 1.0f, 1.0f) + 1e-6f;
    float sd = sqrtf(vs / denom);
    if (cnt == 0) { mn = 0.f; mx = 0.f; }
    float* row = gbuf + (size_t)g * (4 * DIMS);
    row[d] = mean;
    row[DIMS + d] = mn;
    row[2 * DIMS + d] = mx;
    row[3 * DIMS + d] = sd;
}

// out[r, col] = sum_k gbuf[r,k] * w[k,col] + bias[col]; 8 rows per block
__global__ void __launch_bounds__(256)
gemm_kernel(const float* __restrict__ gbuf, const float* __restrict__ w,
            const float* __restrict__ bias, float* __restrict__ out, int B) {
    __shared__ float gl[8 * 512];
    int r0 = blockIdx.x * 8;
    for (int i = threadIdx.x; i < 8 * 512; i += 256) {
        int r = r0 + (i >> 9);
        gl[i] = (r < B) ? gbuf[(size_t)r0 * 512 + i] : 0.f;
    }
    __syncthreads();
    int col = threadIdx.x;
    float acc[8];
    float bv = bias[col];
#pragma unroll
    for (int r = 0; r < 8; ++r) acc[r] = bv;
#pragma unroll 4
    for (int k = 0; k < 512; ++k) {
        float wv = w[k * GD + col];
#pragma unroll
        for (int r = 0; r < 8; ++r) acc[r] += gl[r * 512 + k] * wv;
    }
#pragma unroll
    for (int r = 0; r < 8; ++r) {
        int rr = r0 + r;
        if (rr < B) out[(size_t)rr * GD + col] = acc[r];
    }
}

// ---------- launch ----------
extern "C" void kernel_launch(void* const* d_in, const int* in_sizes, int n_in,
                              void* d_out, int out_size, void* d_ws, size_t ws_size,
                              hipStream_t stream) {
    const int*   e_index = (const int*)d_in[0];
    const float* e       = (const float*)d_in[1];
    const int*   batch   = (const int*)d_in[2];
    const float* fc_w    = (const float*)d_in[3];
    const float* fc_b    = (const float*)d_in[4];
    float* out = (float*)d_out;

    int E = in_sizes[1] / DIMS;
    int B = out_size / GD;

    // workspace layout (all 4B-aligned)
    int* hist   = (int*)d_ws;                  // MAXB
    int* offs   = hist + MAXB;                 // MAXB
    int* cursor = offs + MAXB;                 // MAXB*16 (padded)
    unsigned short* eb = (unsigned short*)(cursor + MAXB * 16);  // E (2B each)
    int* perm   = (int*)(eb + ((E + 1) & ~1)); // E
    float* pbuf = (float*)(perm + E);          // B*PARTS*512
    float* gbuf = pbuf + (size_t)MAXB * PARTS * 512;  // B*512

    hipMemsetAsync(hist, 0, B * sizeof(int), stream);
    hist_kernel<<<1024, 256, 0, stream>>>(e_index, batch, E, B, hist, eb);
    scan_kernel<<<1, MAXB, 0, stream>>>(hist, offs, cursor, B);
    scatter_kernel<<<1024, 256, 0, stream>>>(eb, E, cursor, perm);
    reduce_kernel<<<B * PARTS, 256, 0, stream>>>(e, perm, offs, hist, pbuf);
    combine_kernel<<<(B * DIMS + 255) / 256, 256, 0, stream>>>(pbuf, hist, gbuf, B);
    gemm_kernel<<<(B + 7) / 8, 256, 0, stream>>>(gbuf, fc_w, fc_b, out, B);
}

// Round 3
// 279.459 us; speedup vs baseline: 1.4805x; 1.2373x over previous
//
#include <hip/hip_runtime.h>
#include <math.h>

#define DIMS 128
#define GD 256
#define MAXB 1024
#define NSLOT 8   // edge slots per reduce block (256 thr / 32 dim-groups)
#define PARTS 4   // blocks per graph in reduce phase
#define NBLK 1024 // block decomposition for histogram/scatter

typedef float vfloat4 __attribute__((ext_vector_type(4)));

// ---------- helpers ----------
__device__ __forceinline__ float4 ldnt(const float* p) {
    vfloat4 v = __builtin_nontemporal_load(reinterpret_cast<const vfloat4*>(p));
    return make_float4(v.x, v.y, v.z, v.w);
}
__device__ __forceinline__ float4 f4_add(float4 a, float4 b) {
    return make_float4(a.x + b.x, a.y + b.y, a.z + b.z, a.w + b.w);
}
__device__ __forceinline__ float4 f4_min(float4 a, float4 b) {
    return make_float4(fminf(a.x, b.x), fminf(a.y, b.y), fminf(a.z, b.z), fminf(a.w, b.w));
}
__device__ __forceinline__ float4 f4_max(float4 a, float4 b) {
    return make_float4(fmaxf(a.x, b.x), fmaxf(a.y, b.y), fmaxf(a.z, b.z), fmaxf(a.w, b.w));
}

template <int OP>
__device__ __forceinline__ float4 comb(float4 a, float4 b) {
    if (OP == 0) return f4_add(a, b);
    if (OP == 1) return f4_min(a, b);
    return f4_max(a, b);
}

// reduce the 8 edge-slots (stride 32 in tid) down to slot 0; result valid for tid<32
template <int OP>
__device__ __forceinline__ float4 slot_reduce(float4 v, float4* red) {
    int t = threadIdx.x;
    __syncthreads();
    red[t] = v;
    __syncthreads();
    for (int off = 128; off >= 32; off >>= 1) {
        if (t < off) red[t] = comb<OP>(red[t], red[t + off]);
        __syncthreads();
    }
    return red[t & 31];
}

#define ACC(v) do { \
    sm = f4_add(sm, v); \
    sq = f4_add(sq, make_float4((v).x*(v).x, (v).y*(v).y, (v).z*(v).z, (v).w*(v).w)); \
    mn = f4_min(mn, v); mx = f4_max(mx, v); } while (0)

// ---------- K1: per-block histogram + graph-id cache ----------
__global__ void __launch_bounds__(256)
hist2_kernel(const int* __restrict__ e_index, const int* __restrict__ batch,
             int E, int* __restrict__ hist2, unsigned short* __restrict__ eb) {
    __shared__ int lh[MAXB];
    for (int i = threadIdx.x; i < MAXB; i += 256) lh[i] = 0;
    __syncthreads();
    int b = blockIdx.x;
    int CH = (E + NBLK - 1) / NBLK;
    int lo = b * CH;
    int hi = min(E, lo + CH);
    for (int j = lo + threadIdx.x; j < hi; j += 256) {
        int node = e_index[E + j];       // e_index[1][j]
        int g = batch[node];
        eb[j] = (unsigned short)g;
        atomicAdd(&lh[g], 1);            // LDS atomic only
    }
    __syncthreads();
    for (int i = threadIdx.x; i < MAXB; i += 256)
        hist2[b * MAXB + i] = lh[i];     // coalesced 4 KB per block
}

// ---------- K2: per-graph scan over blocks; hist2[b][g] -> excl prefix; count[g] ----------
__global__ void __launch_bounds__(256)
colscan_kernel(int* __restrict__ hist2, int* __restrict__ count) {
    int g = blockIdx.x;
    int t = threadIdx.x;
    int base = t * 4;
    int v[4];
#pragma unroll
    for (int i = 0; i < 4; ++i) v[i] = hist2[(base + i) * MAXB + g];
    int s0 = 0;
#pragma unroll
    for (int i = 0; i < 4; ++i) { int x = v[i]; v[i] = s0; s0 += x; }
    __shared__ int ls[256];
    ls[t] = s0;
    __syncthreads();
    for (int d = 1; d < 256; d <<= 1) {
        int x = (t >= d) ? ls[t - d] : 0;
        __syncthreads();
        ls[t] += x;
        __syncthreads();
    }
    int excl = ls[t] - s0;
#pragma unroll
    for (int i = 0; i < 4; ++i) hist2[(base + i) * MAXB + g] = excl + v[i];
    if (t == 0) count[g] = ls[255];
}

// ---------- K3: scan count -> offs (exclusive) ----------
__global__ void offscan_kernel(const int* __restrict__ count, int* __restrict__ offs, int B) {
    __shared__ int tmp[MAXB];
    int t = threadIdx.x;
    int v0 = (t < B) ? count[t] : 0;
    tmp[t] = v0;
    __syncthreads();
    for (int d = 1; d < MAXB; d <<= 1) {
        int x = (t >= d) ? tmp[t - d] : 0;
        __syncthreads();
        tmp[t] += x;
        __syncthreads();
    }
    if (t < B) offs[t] = tmp[t] - v0;
}

// ---------- K4: scatter with precomputed bases + LDS cursors (no global atomics) ----------
__global__ void __launch_bounds__(256)
scatter_kernel(const unsigned short* __restrict__ eb, const int* __restrict__ hist2,
               const int* __restrict__ offs, int E, int* __restrict__ perm) {
    __shared__ int lbase[MAXB];
    __shared__ int lcur[MAXB];
    int b = blockIdx.x;
    for (int i = threadIdx.x; i < MAXB; i += 256) {
        lbase[i] = offs[i] + hist2[b * MAXB + i];
        lcur[i] = 0;
    }
    __syncthreads();
    int CH = (E + NBLK - 1) / NBLK;
    int lo = b * CH;
    int hi = min(E, lo + CH);
    for (int j = lo + threadIdx.x; j < hi; j += 256) {
        int g = eb[j];
        int r = atomicAdd(&lcur[g], 1);  // LDS atomic only
        perm[lbase[g] + r] = j;
    }
}

// ---------- K5: one block per (graph, part): partials {sum,min,max,sumsq} ----------
__global__ void __launch_bounds__(256)
reduce_kernel(const float* __restrict__ e, const int* __restrict__ perm,
              const int* __restrict__ offs, const int* __restrict__ count,
              float* __restrict__ pbuf) {
    int bid = blockIdx.x;
    int g = bid >> 2;                // PARTS == 4
    int p = bid & 3;
    int start = offs[g];
    int cnt = count[g];
    int chunk = (cnt + PARTS - 1) / PARTS;
    int base = start + p * chunk;
    int cnt_p = cnt - p * chunk;
    if (cnt_p > chunk) cnt_p = chunk;
    if (cnt_p < 0) cnt_p = 0;
    const int* pp = perm + base;

    int c = threadIdx.x & 31;   // dim group: dims 4c..4c+3
    int s = threadIdx.x >> 5;   // edge slot 0..7

    float4 sm = make_float4(0.f, 0.f, 0.f, 0.f);
    float4 sq = make_float4(0.f, 0.f, 0.f, 0.f);
    float4 mn = make_float4(INFINITY, INFINITY, INFINITY, INFINITY);
    float4 mx = make_float4(-INFINITY, -INFINITY, -INFINITY, -INFINITY);

    int i = s;
    // 4-row software pipeline: indices prefetched one quad ahead, 4 loads in flight
    if (i + 3 * NSLOT < cnt_p) {
        int ia0 = pp[i], ia1 = pp[i + NSLOT], ia2 = pp[i + 2 * NSLOT], ia3 = pp[i + 3 * NSLOT];
        while (true) {
            int ni = i + 4 * NSLOT;
            int na0 = 0, na1 = 0, na2 = 0, na3 = 0;
            bool nok = (ni + 3 * NSLOT < cnt_p);
            if (nok) { na0 = pp[ni]; na1 = pp[ni + NSLOT]; na2 = pp[ni + 2 * NSLOT]; na3 = pp[ni + 3 * NSLOT]; }
            float4 v0 = ldnt(e + (size_t)ia0 * DIMS + c * 4);
            float4 v1 = ldnt(e + (size_t)ia1 * DIMS + c * 4);
            float4 v2 = ldnt(e + (size_t)ia2 * DIMS + c * 4);
            float4 v3 = ldnt(e + (size_t)ia3 * DIMS + c * 4);
            ACC(v0); ACC(v1); ACC(v2); ACC(v3);
            i = ni;
            if (!nok) break;
            ia0 = na0; ia1 = na1; ia2 = na2; ia3 = na3;
        }
    }
    for (; i < cnt_p; i += NSLOT) {
        int r = pp[i];
        float4 v = ldnt(e + (size_t)r * DIMS + c * 4);
        ACC(v);
    }

    __shared__ float4 red[256];
    float4 smr = slot_reduce<0>(sm, red);
    float4 mnr = slot_reduce<1>(mn, red);
    float4 mxr = slot_reduce<2>(mx, red);
    float4 sqr = slot_reduce<0>(sq, red);

    if (threadIdx.x < 32) {
        float* row = pbuf + (size_t)bid * (4 * DIMS);
        int d0 = c * 4;
        *reinterpret_cast<float4*>(row + 0 * DIMS + d0) = smr;
        *reinterpret_cast<float4*>(row + 1 * DIMS + d0) = mnr;
        *reinterpret_cast<float4*>(row + 2 * DIMS + d0) = mxr;
        *reinterpret_cast<float4*>(row + 3 * DIMS + d0) = sqr;
    }
}

// ---------- K6: fused combine + GEMM; 8 graph rows per block ----------
__global__ void __launch_bounds__(256)
gemm_kernel(const float* __restrict__ pbuf, const int* __restrict__ count,
            const float* __restrict__ w, const float* __restrict__ bias,
            float* __restrict__ out, int B) {
    __shared__ float gl[8 * 512];
    int r0 = blockIdx.x * 8;
    int t = threadIdx.x;
    // combine PARTS partials and finalize straight into LDS
#pragma unroll
    for (int q = 0; q < 4; ++q) {
        int pair = q * 256 + t;      // 0..1023 = (r,d)
        int r = pair >> 7;           // 0..7
        int d = pair & 127;
        int g = r0 + r;
        float sm = 0.f, sq = 0.f, mnv = INFINITY, mxv = -INFINITY;
        int cnt = 0;
        if (g < B) {
            cnt = count[g];
            const float* pb = pbuf + (size_t)g * PARTS * 512;
#pragma unroll
            for (int p = 0; p < PARTS; ++p) {
                const float* row = pb + p * 512;
                sm += row[d];
                mnv = fminf(mnv, row[128 + d]);
                mxv = fmaxf(mxv, row[256 + d]);
                sq += row[384 + d];
            }
        }
        float fc = (float)cnt;
        float fcm = fmaxf(fc, 1.0f);
        float mean = sm / fcm;
        float vs = fmaxf(sq - sm * mean, 0.f);
        float sd = sqrtf(vs / (fmaxf(fc - 1.0f, 1.0f) + 1e-6f));
        if (cnt == 0) { mnv = 0.f; mxv = 0.f; }
        gl[r * 512 + 0 * 128 + d] = mean;
        gl[r * 512 + 1 * 128 + d] = mnv;
        gl[r * 512 + 2 * 128 + d] = mxv;
        gl[r * 512 + 3 * 128 + d] = sd;
    }
    __syncthreads();

    int col = t;
    float acc[8];
    float bv = bias[col];
#pragma unroll
    for (int r = 0; r < 8; ++r) acc[r] = bv;
#pragma unroll 4
    for (int k = 0; k < 512; ++k) {
        float wv = w[k * GD + col];
#pragma unroll
        for (int r = 0; r < 8; ++r) acc[r] += gl[r * 512 + k] * wv;
    }
#pragma unroll
    for (int r = 0; r < 8; ++r) {
        int rr = r0 + r;
        if (rr < B) out[(size_t)rr * GD + col] = acc[r];
    }
}

// ---------- launch ----------
extern "C" void kernel_launch(void* const* d_in, const int* in_sizes, int n_in,
                              void* d_out, int out_size, void* d_ws, size_t ws_size,
                              hipStream_t stream) {
    const int*   e_index = (const int*)d_in[0];
    const float* e       = (const float*)d_in[1];
    const int*   batch   = (const int*)d_in[2];
    const float* fc_w    = (const float*)d_in[3];
    const float* fc_b    = (const float*)d_in[4];
    float* out = (float*)d_out;

    int E = in_sizes[1] / DIMS;
    int B = out_size / GD;

    // workspace layout (all 4B-aligned)
    int* hist2 = (int*)d_ws;                         // NBLK*MAXB = 4 MB
    int* count = hist2 + (size_t)NBLK * MAXB;        // MAXB
    int* offs  = count + MAXB;                       // MAXB
    unsigned short* eb = (unsigned short*)(offs + MAXB);  // E ushorts
    int* perm  = (int*)(eb + (((size_t)E + 1) & ~(size_t)1)); // E
    float* pbuf = (float*)(perm + E);                // MAXB*PARTS*512 = 8 MB

    hist2_kernel<<<NBLK, 256, 0, stream>>>(e_index, batch, E, hist2, eb);
    colscan_kernel<<<MAXB, 256, 0, stream>>>(hist2, count);
    offscan_kernel<<<1, MAXB, 0, stream>>>(count, offs, B);
    scatter_kernel<<<NBLK, 256, 0, stream>>>(eb, hist2, offs, E, perm);
    reduce_kernel<<<B * PARTS, 256, 0, stream>>>(e, perm, offs, count, pbuf);
    gemm_kernel<<<(B + 7) / 8, 256, 0, stream>>>(pbuf, count, fc_w, fc_b, out, B);
}